// Round 18
// baseline (1093.148 us; speedup 1.0000x reference)
//
#include <hip/hip_runtime.h>

typedef __attribute__((ext_vector_type(8))) _Float16 half8;
typedef __attribute__((ext_vector_type(4))) _Float16 half4;
typedef __attribute__((ext_vector_type(4))) float f32x4;

#define N_NODES 6272
#define CDIM    2048
#define HK      1024     // split-K half width
#define ODIM    512
#define NPAN    49       // 6272 / 128 node panels
#define NSLOT   392      // 49 panels * 8 candidates per node
#define GRID_G  1232     // 8 x 154 (1225 live triangle tiles + 7 dead)
#define GRID_H1 392      // hgemm layer-1 blocks (64x128 tiles)
#define E2      0.5f     // 2*E, E=0.25 ~ 7 sigma of hi-only screen d2 error

// ---------------- workspace layout (bytes) ----------------
// split-K screen operand: xq0 = dims [0,1024), xq1 = dims [1024,2048),
// 12.8MB apart -> dual far-apart DRAM streams during staging (r11 mechanism).
#define XQ0_OFF    0ul                 // 12,845,056
#define XQ1_OFF    12845056ul          // 12,845,056 -> 25,690,112
#define CANDV_OFF  25690112ul          // 9,834,496
#define CANDI_OFF  35524608ul          // 4,917,248
#define SQ_OFF     40441856ul
#define KNN_OFF    40466944ul
#define DINV_OFF   41520640ul
#define RPTR_OFF   41545728ul
#define COL_OFF    41571072ul
#define W1T0_OFF   41796864ul          // 1,048,576  (dims [0,1024))
#define W1T1_OFF   42845440ul          // 1,048,576  (dims [1024,2048))
#define W2T_OFF    43894016ul          // 524,288 -> 44,418,304
#define H1H_OFF    44418304ul          // f16 6.4MB -> 50,843,648
#define HW_OFF     50843648ul          // f16 6.4MB (own region)

// ---------------- async global->LDS (16B per lane, wave-uniform LDS base) ----
__device__ __forceinline__ void gld_lds16(const void* g, void* l) {
    __builtin_amdgcn_global_load_lds(
        (const __attribute__((address_space(1))) void*)g,
        (__attribute__((address_space(3))) void*)l, 16, 0, 0);
}

// BK=64 tile: [row][128B]; 16B slot b holds logical k-block b ^ (row&7).
__device__ __forceinline__ half8 frag_read(const char* base, int row, int s, int lane) {
    int b = (s * 4 + (lane >> 4)) ^ (row & 7);
    return *(const half8*)(base + row * 128 + b * 16);
}

#define MF(a, b, c) __builtin_amdgcn_mfma_f32_16x16x32_f16(a, b, c, 0, 0, 0)

// ------- prep: fused x->(xq0,xq1,sq) + W1^T(split) + W2^T, one launch -------
__global__ __launch_bounds__(256) void prep_kernel(const float* __restrict__ x,
        _Float16* __restrict__ xq0, _Float16* __restrict__ xq1,
        float* __restrict__ sq,
        const float* __restrict__ W1, _Float16* __restrict__ w1t0,
        _Float16* __restrict__ w1t1,
        const float* __restrict__ W2, _Float16* __restrict__ w2t) {
    __shared__ float tile[64][65];
    int bid = blockIdx.x, tid = threadIdx.x;
    if (bid < 1568) {
        int i = bid * 4 + (tid >> 6);
        int t = tid & 63;
        const float* row = x + (size_t)i * CDIM;
        float s = 0.f;
#pragma unroll
        for (int k8 = 0; k8 < 8; k8++) {
            int k = (k8 * 64 + t) * 4;
            float4 v = *(const float4*)(row + k);
            half4 h;
            h[0] = (_Float16)v.x; h[1] = (_Float16)v.y;
            h[2] = (_Float16)v.z; h[3] = (_Float16)v.w;
            if (k8 < 4) *(half4*)(xq0 + (size_t)i * HK + k)      = h;
            else        *(half4*)(xq1 + (size_t)i * HK + k - HK) = h;
            s += v.x * v.x + v.y * v.y + v.z * v.z + v.w * v.w;
        }
#pragma unroll
        for (int off = 32; off; off >>= 1) s += __shfl_down(s, off, 64);
        if (t == 0) sq[i] = s;
        return;
    }
    // weight transpose tiles
    const float* W; int K, N, idx;
    if (bid < 1824) { idx = bid - 1568; W = W1; K = CDIM; N = ODIM; }
    else            { idx = bid - 1824; W = W2; K = ODIM; N = ODIM; }
    int nkb = K / 64;
    int kb = (idx % nkb) * 64, nb = (idx / nkb) * 64;
    int r = tid >> 2, c0 = (tid & 3) * 16;
#pragma unroll
    for (int u = 0; u < 4; u++) {
        float4 v = *(const float4*)(W + (size_t)(kb + r) * N + nb + c0 + u * 4);
        tile[r][c0 + u * 4 + 0] = v.x; tile[r][c0 + u * 4 + 1] = v.y;
        tile[r][c0 + u * 4 + 2] = v.z; tile[r][c0 + u * 4 + 3] = v.w;
    }
    __syncthreads();
    int rn = tid >> 2, ck0 = (tid & 3) * 16;
    if (bid < 1824) {
        _Float16* Wt = (kb < HK) ? w1t0 : w1t1;
        int kcol = (kb < HK) ? kb : kb - HK;
#pragma unroll
        for (int u = 0; u < 4; u++) {
            half4 o;
#pragma unroll
            for (int j = 0; j < 4; j++) o[j] = (_Float16)tile[ck0 + u * 4 + j][rn];
            *(half4*)(Wt + (size_t)(nb + rn) * HK + kcol + ck0 + u * 4) = o;
        }
    } else {
#pragma unroll
        for (int u = 0; u < 4; u++) {
            half4 o;
#pragma unroll
            for (int j = 0; j < 4; j++) o[j] = (_Float16)tile[ck0 + u * 4 + j][rn];
            *(half4*)(w2t + (size_t)(nb + rn) * ODIM + kb + ck0 + u * 4) = o;
        }
    }
}

// ==== MERGED: gram screen (blocks 0..1231) + hgemm layer-1 (1232..1623) ====
// Staging: per 128B LDS line, logical slots 0-3 come from xq0, 4-7 from xq1
// (12.8MB apart) -> dual far-apart DRAM streams. Chunk c covers dims
// {32c..32c+32} u {1024+32c..+32}; dot is order-invariant.
__global__ __launch_bounds__(256, 4) void gram_hgemm_kernel(
        const _Float16* __restrict__ xq0, const _Float16* __restrict__ xq1,
        const float* __restrict__ sq,
        float* __restrict__ candv, unsigned short* __restrict__ candi,
        const _Float16* __restrict__ w1t0, const _Float16* __restrict__ w1t1,
        _Float16* __restrict__ hw) {
    __shared__ char lds[32768];
    int tid = threadIdx.x, lane = tid & 63, wave = tid >> 6;
    int l15 = lane & 15, kg = lane >> 4;
    int r_in = lane >> 3;
    int skb = (lane & 7) ^ r_in;           // logical slot 0..7
    const int koff = (skb & 3) * 8;        // element offset within the half
    const bool hi_half = (skb >= 4);

    if (blockIdx.x >= GRID_G) {
        // ---------------- hgemm layer-1: 64x128 tile, XCD-swizzled ----------------
        int hb = blockIdx.x - GRID_G;
        const int nit = N_NODES / 64;          // 98 i-tiles
        int per = GRID_H1 >> 3;                // 49
        int swz = (hb & 7) * per + (hb >> 3);
        int i0 = (swz % nit) * 64, j0 = (swz / nit) * 128;
        const _Float16* Asrc = hi_half ? xq1 : xq0;
        const _Float16* Bsrc = hi_half ? w1t1 : w1t0;
        f32x4 acc[4][2] = {};
#pragma unroll 1
        for (int cc = 0; cc < 32; cc++) {
            int kk = cc * 32 + koff;
            __syncthreads();
#pragma unroll
            for (int g = 0; g < 6; g++) {      // 24 segs: A 8, B 16; 6 per wave
                int sg = wave * 6 + g;
                if (sg < 8) {
                    gld_lds16(Asrc + (size_t)(i0 + sg * 8 + r_in) * HK + kk,
                              lds + sg * 1024);
                } else {
                    int seg = sg - 8;
                    gld_lds16(Bsrc + (size_t)(j0 + seg * 8 + r_in) * HK + kk,
                              lds + 8192 + seg * 1024);
                }
            }
            __syncthreads();
#pragma unroll
            for (int s = 0; s < 2; s++) {
                half8 a[4];
#pragma unroll
                for (int m = 0; m < 4; m++) a[m] = frag_read(lds, m * 16 + l15, s, lane);
#pragma unroll
                for (int n = 0; n < 2; n++) {
                    half8 b = frag_read(lds + 8192, wave * 32 + n * 16 + l15, s, lane);
#pragma unroll
                    for (int m = 0; m < 4; m++) acc[m][n] = MF(a[m], b, acc[m][n]);
                }
            }
        }
#pragma unroll
        for (int m = 0; m < 4; m++)
#pragma unroll
            for (int n = 0; n < 2; n++)
#pragma unroll
                for (int r = 0; r < 4; r++) {
                    int row = i0 + m * 16 + kg * 4 + r;
                    int colj = j0 + wave * 32 + n * 16 + l15;
                    hw[(size_t)row * ODIM + colj] = (_Float16)acc[m][n][r];
                }
        return;
    }

    // ---------------- gram screen ----------------
    float* S = (float*)lds;                                  // [128][33] 16.9KB
    float* topv = (float*)(lds + 16896);                     // [128][9]  4.6KB
    unsigned short* topi = (unsigned short*)(lds + 21504);   // [128][10] 2.6KB
#define TOPV(r, k) topv[(r) * 9 + (k)]
#define TOPI(r, k) topi[(r) * 10 + (k)]
    int wr = wave >> 1, wc = wave & 1;

    // bijective XCD chunking over t-major triangle raster (1225 = 8*153 + 1)
    int xcd = blockIdx.x & 7, loc = blockIdx.x >> 3;
    if (xcd != 0 && loc >= 153) return;
    int raster = (xcd == 0) ? loc : (154 + (xcd - 1) * 153 + loc);
    int t = (int)((sqrtf(8.f * (float)raster + 1.f) - 1.f) * 0.5f);
    while ((t + 1) * (t + 2) / 2 <= raster) t++;
    while (t * (t + 1) / 2 > raster) t--;
    int p = raster - t * (t + 1) / 2;                          // p <= t
    size_t i0 = (size_t)p * 128, j0 = (size_t)t * 128;

    f32x4 acc[4][4] = {};
    const _Float16* Ssrc = hi_half ? xq1 : xq0;

#pragma unroll 1
    for (int c = 0; c < 32; c++) {
        int kk = c * 32 + koff;
#pragma unroll
        for (int g = 0; g < 8; g++) {      // 32 segs (8 rows x 128B), 8 per wave
            int sg = wave * 8 + g;
            int tI = sg >> 4, seg = sg & 15;
            size_t row = (tI ? j0 : i0) + (size_t)(seg * 8 + r_in);
            gld_lds16(Ssrc + row * HK + kk, lds + tI * 16384 + seg * 1024);
        }
        __syncthreads();
#pragma unroll
        for (int s = 0; s < 2; s++) {
            half8 a4[4];
#pragma unroll
            for (int m = 0; m < 4; m++)
                a4[m] = frag_read(lds, wr * 64 + m * 16 + l15, s, lane);
#pragma unroll
            for (int n = 0; n < 4; n++) {
                half8 b = frag_read(lds + 16384, wc * 64 + n * 16 + l15, s, lane);
#pragma unroll
                for (int m = 0; m < 4; m++) acc[m][n] = MF(a4[m], b, acc[m][n]);
            }
        }
        __syncthreads();
    }

    float sqi[4][4];
#pragma unroll
    for (int m = 0; m < 4; m++)
#pragma unroll
        for (int r = 0; r < 4; r++)
            sqi[m][r] = sq[(int)i0 + wr * 64 + m * 16 + kg * 4 + r];
    float sqj[4];
#pragma unroll
    for (int n = 0; n < 4; n++)
        sqj[n] = sq[(int)j0 + wc * 64 + n * 16 + l15];

    if (tid < 128) {
#pragma unroll
        for (int k = 0; k < 8; k++) { TOPV(tid, k) = 3.4e38f; TOPI(tid, k) = 0xFFFF; }
    }

    // ---- row pass ----
#pragma unroll
    for (int cs = 0; cs < 4; cs++) {
        __syncthreads();
        if (wc == (cs >> 1)) {
            const int n0 = (cs & 1) * 2;
#pragma unroll
            for (int m = 0; m < 4; m++)
#pragma unroll
                for (int nn = 0; nn < 2; nn++)
#pragma unroll
                    for (int r = 0; r < 4; r++) {
                        int row = wr * 64 + m * 16 + kg * 4 + r;
                        float d2 = sqi[m][r] + sqj[n0 + nn] - 2.f * acc[m][n0 + nn][r];
                        S[row * 33 + nn * 16 + l15] = d2;
                    }
        }
        __syncthreads();
        if (tid < 128) {
            int r = tid, gi = (int)i0 + r;
            int cbase = (int)j0 + cs * 32;
#pragma unroll 4
            for (int jj = 0; jj < 32; jj++) {
                int gj = cbase + jj;
                if (gj == gi) continue;
                float v = S[r * 33 + jj];
                float wv = TOPV(r, 7); int wi = TOPI(r, 7);
                if (v < wv || (v == wv && gj < wi)) {
                    int pos = 7;
                    while (pos > 0) {
                        float pv = TOPV(r, pos - 1); int pi = TOPI(r, pos - 1);
                        if (v < pv || (v == pv && gj < pi)) {
                            TOPV(r, pos) = pv; TOPI(r, pos) = (unsigned short)pi; pos--;
                        } else break;
                    }
                    TOPV(r, pos) = v; TOPI(r, pos) = (unsigned short)gj;
                }
            }
        }
    }
    __syncthreads();
    if (tid < 128) {
        int gi = (int)i0 + tid;
#pragma unroll
        for (int k = 0; k < 8; k++) {
            candv[(size_t)gi * NSLOT + t * 8 + k] = TOPV(tid, k);
            candi[(size_t)gi * NSLOT + t * 8 + k] = TOPI(tid, k);
        }
#pragma unroll
        for (int k = 0; k < 8; k++) { TOPV(tid, k) = 3.4e38f; TOPI(tid, k) = 0xFFFF; }
    }

    // ---- column pass (off-diagonal only) ----
    if (p < t) {
#pragma unroll
        for (int ss = 0; ss < 4; ss++) {
            __syncthreads();
            if (wr == (ss >> 1)) {
                const int mb = (ss & 1) * 2;
#pragma unroll
                for (int mm = 0; mm < 2; mm++)
#pragma unroll
                    for (int n = 0; n < 4; n++)
#pragma unroll
                        for (int r = 0; r < 4; r++) {
                            int rl  = mm * 16 + kg * 4 + r;
                            int col = wc * 64 + n * 16 + l15;
                            float d2 = sqi[mb + mm][r] + sqj[n] - 2.f * acc[mb + mm][n][r];
                            S[col * 33 + rl] = d2;
                        }
            }
            __syncthreads();
            if (tid < 128) {
                int cc = tid;
                int rbase = (int)i0 + ss * 32;
#pragma unroll 4
                for (int jj = 0; jj < 32; jj++) {
                    int gi = rbase + jj;
                    float v = S[cc * 33 + jj];
                    float wv = TOPV(cc, 7); int wi = TOPI(cc, 7);
                    if (v < wv || (v == wv && gi < wi)) {
                        int pos = 7;
                        while (pos > 0) {
                            float pv = TOPV(cc, pos - 1); int pi = TOPI(cc, pos - 1);
                            if (v < pv || (v == pv && gi < pi)) {
                                TOPV(cc, pos) = pv; TOPI(cc, pos) = (unsigned short)pi; pos--;
                            } else break;
                        }
                        TOPV(cc, pos) = v; TOPI(cc, pos) = (unsigned short)gi;
                    }
                }
            }
        }
        __syncthreads();
        if (tid < 128) {
            int gj = (int)j0 + tid;
#pragma unroll
            for (int k = 0; k < 8; k++) {
                candv[(size_t)gj * NSLOT + p * 8 + k] = TOPV(tid, k);
                candi[(size_t)gj * NSLOT + p * 8 + k] = TOPI(tid, k);
            }
        }
    }
#undef TOPV
#undef TOPI
}

// --- fused: merge 49 lists -> approx top-16 -> BAND-limited exact refine -> knn ---
__global__ __launch_bounds__(256) void knn_select_kernel(
        const float* __restrict__ candv, const unsigned short* __restrict__ candi,
        const float* __restrict__ x, const float* __restrict__ sq,
        int* __restrict__ knn) {
    int node = blockIdx.x * 4 + (threadIdx.x >> 6);
    int lane = threadIdx.x & 63;
    const float* cv = candv + (size_t)node * NSLOT;
    const unsigned short* ci = candi + (size_t)node * NSLOT;
    float v[7]; int ix[7];
#pragma unroll
    for (int u = 0; u < 7; u++) {
        int s = u * 64 + lane;
        bool ok = (s < NSLOT);
        v[u]  = ok ? cv[s] : 3.4e38f;
        ix[u] = ok ? (int)ci[s] : 0x7fffffff;
    }
    float myv16 = 3.4e38f; int myc = 0x7fffffff;   // lane k<16 owns k-th candidate
#pragma unroll 1
    for (int k = 0; k < 16; k++) {
        float bv = v[0]; int bi = ix[0];
#pragma unroll
        for (int u = 1; u < 7; u++)
            if (v[u] < bv || (v[u] == bv && ix[u] < bi)) { bv = v[u]; bi = ix[u]; }
#pragma unroll
        for (int off = 32; off; off >>= 1) {
            float ov = __shfl_xor(bv, off, 64);
            int   oi = __shfl_xor(bi, off, 64);
            if (ov < bv || (ov == bv && oi < bi)) { bv = ov; bi = oi; }
        }
        if (lane == k) { myv16 = bv; myc = bi; }
#pragma unroll
        for (int u = 0; u < 7; u++)
            if (ix[u] == bi) { v[u] = 3.4e38f; ix[u] = 0x7fffffff; }
    }
    float v7 = __shfl(myv16, 7, 64), v8 = __shfl(myv16, 8, 64);
    if (v8 - v7 > E2) {                            // fast path: set provably exact
        if (lane < 8) knn[(size_t)node * 8 + lane] = myc;
        return;
    }
    bool isc  = (lane < 16);
    bool cin  = isc && (myv16 < v7 - E2);
    bool cout = isc && (myv16 > v8 + E2);
    bool band = isc && !cin && !cout;
    unsigned long long bm = __ballot(band);
    float fv = myv16;
    if (cin)  fv = myv16 - 1e9f;
    if (cout) fv = myv16 + 1e9f;

    const float* xi = x + (size_t)node * CDIM;
    float4 a[8];
#pragma unroll
    for (int g = 0; g < 8; g++) a[g] = *(const float4*)(xi + (g * 64 + lane) * 4);
    float sqi = sq[node];
#pragma unroll 1
    for (int c = 0; c < 16; c++) {
        if (!((bm >> c) & 1ull)) continue;
        int j = __shfl(myc, c, 64);
        const float* xj = x + (size_t)j * CDIM;
        float s = 0.f;
#pragma unroll
        for (int g = 0; g < 8; g++) {
            float4 b = *(const float4*)(xj + (g * 64 + lane) * 4);
            s = fmaf(a[g].x, b.x, s); s = fmaf(a[g].y, b.y, s);
            s = fmaf(a[g].z, b.z, s); s = fmaf(a[g].w, b.w, s);
        }
#pragma unroll
        for (int off = 32; off; off >>= 1) s += __shfl_down(s, off, 64);
        float d2 = sqi + sq[j] - 2.f * s;
        d2 = __shfl(d2, 0, 64);
        if (lane == c) fv = d2;
    }
    float rv = (lane < 16) ? fv : 3.4e38f;
    int   ri = (lane < 16) ? myc : 0x7fffffff;
#pragma unroll 1
    for (int k = 0; k < 8; k++) {
        float bv = rv; int bi = ri;
#pragma unroll
        for (int off = 8; off; off >>= 1) {
            float ov = __shfl_xor(bv, off, 64);
            int   oi = __shfl_xor(bi, off, 64);
            if (ov < bv || (ov == bv && oi < bi)) { bv = ov; bi = oi; }
        }
        bv = __shfl(bv, lane & 15, 64); bi = __shfl(bi, lane & 15, 64);
        if (lane == 0) knn[(size_t)node * 8 + k] = bi;
        if (ri == bi) { rv = 3.4e38f; ri = 0x7fffffff; }
    }
}

// ---- graph build, single block: deg/cnt/rptr in LDS, one launch -----
__global__ __launch_bounds__(1024) void graph_build_kernel(
        const int* __restrict__ knn, float* __restrict__ dinv,
        int* __restrict__ row_ptr, int* __restrict__ col) {
    __shared__ int deg_l[N_NODES];
    __shared__ int cnt_l[N_NODES];
    __shared__ int rp_l[N_NODES];
    __shared__ int partial[1024];
    int tid = threadIdx.x;
    for (int i = tid; i < N_NODES; i += 1024) { deg_l[i] = 1; cnt_l[i] = 0; }
    __syncthreads();
    for (int e = tid; e < N_NODES * 8; e += 1024) atomicAdd(&deg_l[knn[e]], 1);
    __syncthreads();
    const int CH = 7;
    int start = tid * CH;
    int end = start + CH; if (end > N_NODES) end = N_NODES;
    int s = 0;
    for (int i = start; i < end; i++) s += deg_l[i];
    partial[tid] = s;
    __syncthreads();
    if (tid == 0) {
        int run = 0;
        for (int k = 0; k < 1024; k++) { int vv = partial[k]; partial[k] = run; run += vv; }
        row_ptr[N_NODES] = run;
    }
    __syncthreads();
    int run = partial[tid];
    for (int i = start; i < end; i++) {
        rp_l[i] = run; row_ptr[i] = run;
        dinv[i] = rsqrtf((float)deg_l[i]);
        run += deg_l[i];
    }
    __syncthreads();
    for (int i = tid; i < N_NODES; i += 1024) {
        int p0 = rp_l[i] + atomicAdd(&cnt_l[i], 1);
        col[p0] = i;
#pragma unroll
        for (int j = 0; j < 8; j++) {
            int d = knn[i * 8 + j];
            int q = rp_l[d] + atomicAdd(&cnt_l[d], 1);
            col[q] = i;
        }
    }
}

// ---- fp16 MFMA GEMM, 64x128 tiles, f16 out, XCD-swizzled (layer 2, K=512) ----
__global__ __launch_bounds__(256) void hgemm_nt_kernel(
        const _Float16* __restrict__ A, const _Float16* __restrict__ Bt,
        _Float16* __restrict__ C, int M, int N, int K) {
    __shared__ char lds[24576];        // A 8KB | B 16KB
    int tid = threadIdx.x, lane = tid & 63, wave = tid >> 6;
    int l15 = lane & 15, kg = lane >> 4;
    int nt = N >> 7;
    int nblk = (M >> 6) * nt;
    int per = nblk >> 3;
    int swz = (blockIdx.x & 7) * per + (blockIdx.x >> 3);
    int i0 = (swz % (M >> 6)) * 64, j0 = (swz / (M >> 6)) * 128;
    f32x4 acc[4][2] = {};

    int r_in = lane >> 3;
    int skb = (lane & 7) ^ r_in;

#pragma unroll 1
    for (int kk = 0; kk < K; kk += 64) {
        __syncthreads();
#pragma unroll
        for (int g = 0; g < 6; g++) {
            int sg = wave * 6 + g;
            if (sg < 8) {
                gld_lds16(A + (size_t)(i0 + sg * 8 + r_in) * K + kk + skb * 8,
                          lds + sg * 1024);
            } else {
                int seg = sg - 8;
                gld_lds16(Bt + (size_t)(j0 + seg * 8 + r_in) * K + kk + skb * 8,
                          lds + 8192 + seg * 1024);
            }
        }
        __syncthreads();
#pragma unroll
        for (int s = 0; s < 2; s++) {
            half8 a[4];
#pragma unroll
            for (int m = 0; m < 4; m++) a[m] = frag_read(lds, m * 16 + l15, s, lane);
#pragma unroll
            for (int n = 0; n < 2; n++) {
                half8 b = frag_read(lds + 8192, wave * 32 + n * 16 + l15, s, lane);
#pragma unroll
                for (int m = 0; m < 4; m++) acc[m][n] = MF(a[m], b, acc[m][n]);
            }
        }
    }
#pragma unroll
    for (int m = 0; m < 4; m++)
#pragma unroll
        for (int n = 0; n < 2; n++)
#pragma unroll
            for (int r = 0; r < 4; r++) {
                int row = i0 + m * 16 + kg * 4 + r;
                int colj = j0 + wave * 32 + n * 16 + l15;
                C[(size_t)row * N + colj] = (_Float16)acc[m][n][r];
            }
}

// --- GCN aggregation (f16 in): out[d] = relu(dinv[d]*sum hw[s]*dinv[s] + b) ---
template <bool HALF_OUT>
__global__ __launch_bounds__(256) void aggregate_kernel(
        const _Float16* __restrict__ hw, const int* __restrict__ row_ptr,
        const int* __restrict__ col, const float* __restrict__ dinv,
        const float* __restrict__ bias, void* __restrict__ outp) {
    int node = blockIdx.x * 4 + (threadIdx.x >> 6);
    int lane = threadIdx.x & 63;
    int e0 = row_ptr[node], e1 = row_ptr[node + 1];
    float acc[8] = {};
    for (int e = e0; e < e1; e++) {
        int s = col[e];
        float w = dinv[s];
        half8 v = *(const half8*)(hw + (size_t)s * ODIM + lane * 8);
#pragma unroll
        for (int j = 0; j < 8; j++) acc[j] = fmaf(w, (float)v[j], acc[j]);
    }
    float wd = dinv[node];
    float4 b0 = *(const float4*)(bias + lane * 8);
    float4 b1 = *(const float4*)(bias + lane * 8 + 4);
    float o[8];
    o[0] = fmaxf(fmaf(acc[0], wd, b0.x), 0.f);
    o[1] = fmaxf(fmaf(acc[1], wd, b0.y), 0.f);
    o[2] = fmaxf(fmaf(acc[2], wd, b0.z), 0.f);
    o[3] = fmaxf(fmaf(acc[3], wd, b0.w), 0.f);
    o[4] = fmaxf(fmaf(acc[4], wd, b1.x), 0.f);
    o[5] = fmaxf(fmaf(acc[5], wd, b1.y), 0.f);
    o[6] = fmaxf(fmaf(acc[6], wd, b1.z), 0.f);
    o[7] = fmaxf(fmaf(acc[7], wd, b1.w), 0.f);
    if (HALF_OUT) {
        half8 h;
#pragma unroll
        for (int j = 0; j < 8; j++) h[j] = (_Float16)o[j];
        *(half8*)((_Float16*)outp + (size_t)node * ODIM + lane * 8) = h;
    } else {
        float* out = (float*)outp;
        float4 f0 = {o[0], o[1], o[2], o[3]}, f1 = {o[4], o[5], o[6], o[7]};
        *(float4*)(out + (size_t)node * ODIM + lane * 8)     = f0;
        *(float4*)(out + (size_t)node * ODIM + lane * 8 + 4) = f1;
    }
}

extern "C" void kernel_launch(void* const* d_in, const int* in_sizes, int n_in,
                              void* d_out, int out_size, void* d_ws, size_t ws_size,
                              hipStream_t stream) {
    const float* x  = (const float*)d_in[0];
    const float* W1 = (const float*)d_in[1];
    const float* b1 = (const float*)d_in[2];
    const float* W2 = (const float*)d_in[3];
    const float* b2 = (const float*)d_in[4];
    float* out = (float*)d_out;
    char* ws = (char*)d_ws;

    _Float16* xq0  = (_Float16*)(ws + XQ0_OFF);
    _Float16* xq1  = (_Float16*)(ws + XQ1_OFF);
    float* candv   = (float*)(ws + CANDV_OFF);
    unsigned short* candi = (unsigned short*)(ws + CANDI_OFF);
    float* sq      = (float*)(ws + SQ_OFF);
    int*   knn     = (int*)  (ws + KNN_OFF);
    float* dinv    = (float*)(ws + DINV_OFF);
    int*   row_ptr = (int*)  (ws + RPTR_OFF);
    int*   col     = (int*)  (ws + COL_OFF);
    _Float16* w1t0 = (_Float16*)(ws + W1T0_OFF);
    _Float16* w1t1 = (_Float16*)(ws + W1T1_OFF);
    _Float16* w2t  = (_Float16*)(ws + W2T_OFF);
    _Float16* hw   = (_Float16*)(ws + HW_OFF);
    _Float16* h1h  = (_Float16*)(ws + H1H_OFF);

    prep_kernel<<<1888, 256, 0, stream>>>(x, xq0, xq1, sq, W1, w1t0, w1t1, W2, w2t);
    gram_hgemm_kernel<<<GRID_G + GRID_H1, 256, 0, stream>>>(xq0, xq1, sq, candv, candi,
                                                            w1t0, w1t1, hw);
    knn_select_kernel<<<N_NODES / 4, 256, 0, stream>>>(candv, candi, x, sq, knn);
    graph_build_kernel<<<1, 1024, 0, stream>>>(knn, dinv, row_ptr, col);

    aggregate_kernel<true><<<N_NODES / 4, 256, 0, stream>>>(hw, row_ptr, col, dinv, b1, (void*)h1h);
    hgemm_nt_kernel<<<(N_NODES / 64) * (ODIM / 128), 256, 0, stream>>>(h1h, w2t, hw, N_NODES, ODIM, ODIM);
    aggregate_kernel<false><<<N_NODES / 4, 256, 0, stream>>>(hw, row_ptr, col, dinv, b2, (void*)out);
}

// Round 19
// 1081.383 us; speedup vs baseline: 1.0109x; 1.0109x over previous
//
#include <hip/hip_runtime.h>

typedef __attribute__((ext_vector_type(8))) _Float16 half8;
typedef __attribute__((ext_vector_type(4))) _Float16 half4;
typedef __attribute__((ext_vector_type(4))) float f32x4;

#define N_NODES 6272
#define CDIM    2048
#define ODIM    512
#define NPAN    49       // 6272 / 128 node panels
#define NSLOT   392      // 49 panels * 8 candidates per node
#define GRID_G  1232     // 8 x 154 (1225 live triangle tiles + 7 dead)
#define GRID_H1 392      // hgemm layer-1 blocks (64x128 tiles)
#define E2      0.5f     // 2*E, E=0.25 ~ 7 sigma of hi-only screen d2 error

// ---------------- workspace layout (bytes) ----------------
#define XHI_OFF    0ul                 // 25,690,112
#define CANDV_OFF  25690112ul          // 9,834,496
#define CANDI_OFF  35524608ul          // 4,917,248
#define SQ_OFF     40441856ul
#define KNN_OFF    40466944ul
#define CNT_OFF    40667648ul          // 25,088 (re-added for parallel scatter)
#define DEG_OFF    40692736ul          // 25,088
#define DINV_OFF   41520640ul
#define RPTR_OFF   41545728ul
#define COL_OFF    41571072ul
#define W1T_OFF    41796864ul
#define W2T_OFF    43894016ul          // -> 44,418,304
#define H1H_OFF    44418304ul          // f16 6.4MB -> 50,843,648
#define HW_OFF     50843648ul          // f16 6.4MB (own region)

// ---------------- async global->LDS (16B per lane, wave-uniform LDS base) ----
__device__ __forceinline__ void gld_lds16(const void* g, void* l) {
    __builtin_amdgcn_global_load_lds(
        (const __attribute__((address_space(1))) void*)g,
        (__attribute__((address_space(3))) void*)l, 16, 0, 0);
}

// BK=64 tile: [row][128B]; 16B slot b holds logical k-block b ^ (row&7).
__device__ __forceinline__ half8 frag_read(const char* base, int row, int s, int lane) {
    int b = (s * 4 + (lane >> 4)) ^ (row & 7);
    return *(const half8*)(base + row * 128 + b * 16);
}

#define MF(a, b, c) __builtin_amdgcn_mfma_f32_16x16x32_f16(a, b, c, 0, 0, 0)

// ------- prep: fused x->(xhi,sq) + W1^T + W2^T (independent tiles, one launch) -------
__global__ __launch_bounds__(256) void prep_kernel(const float* __restrict__ x,
        _Float16* __restrict__ xhi, float* __restrict__ sq,
        const float* __restrict__ W1, _Float16* __restrict__ w1t,
        const float* __restrict__ W2, _Float16* __restrict__ w2t) {
    __shared__ float tile[64][65];
    int bid = blockIdx.x, tid = threadIdx.x;
    if (bid < 1568) {
        int i = bid * 4 + (tid >> 6);
        int t = tid & 63;
        const float* row = x + (size_t)i * CDIM;
        _Float16* hrow = xhi + (size_t)i * CDIM;
        float s = 0.f;
#pragma unroll
        for (int k = 0; k < 8; k++) {
            float4 v = *(const float4*)(row + (k * 64 + t) * 4);
            half4 h;
            h[0] = (_Float16)v.x; h[1] = (_Float16)v.y;
            h[2] = (_Float16)v.z; h[3] = (_Float16)v.w;
            *(half4*)(hrow + (k * 64 + t) * 4) = h;
            s += v.x * v.x + v.y * v.y + v.z * v.z + v.w * v.w;
        }
#pragma unroll
        for (int off = 32; off; off >>= 1) s += __shfl_down(s, off, 64);
        if (t == 0) sq[i] = s;
        return;
    }
    const float* W; _Float16* Wt; int K, N, idx;
    if (bid < 1824) { idx = bid - 1568; W = W1; Wt = w1t; K = CDIM; N = ODIM; }
    else            { idx = bid - 1824; W = W2; Wt = w2t; K = ODIM; N = ODIM; }
    int nkb = K / 64;
    int kb = (idx % nkb) * 64, nb = (idx / nkb) * 64;
    int r = tid >> 2, c0 = (tid & 3) * 16;
#pragma unroll
    for (int u = 0; u < 4; u++) {
        float4 v = *(const float4*)(W + (size_t)(kb + r) * N + nb + c0 + u * 4);
        tile[r][c0 + u * 4 + 0] = v.x; tile[r][c0 + u * 4 + 1] = v.y;
        tile[r][c0 + u * 4 + 2] = v.z; tile[r][c0 + u * 4 + 3] = v.w;
    }
    __syncthreads();
    int rn = tid >> 2, ck0 = (tid & 3) * 16;
#pragma unroll
    for (int u = 0; u < 4; u++) {
        half4 o;
#pragma unroll
        for (int j = 0; j < 4; j++) o[j] = (_Float16)tile[ck0 + u * 4 + j][rn];
        *(half4*)(Wt + (size_t)(nb + rn) * K + kb + ck0 + u * 4) = o;
    }
}

// ==== MERGED: gram screen (blocks 0..1231) + hgemm layer-1 (1232..1623) ====
__global__ __launch_bounds__(256, 4) void gram_hgemm_kernel(
        const _Float16* __restrict__ xhi, const float* __restrict__ sq,
        float* __restrict__ candv, unsigned short* __restrict__ candi,
        const _Float16* __restrict__ w1t, _Float16* __restrict__ hw) {
    __shared__ char lds[32768];
    int tid = threadIdx.x, lane = tid & 63, wave = tid >> 6;
    int l15 = lane & 15, kg = lane >> 4;
    int r_in = lane >> 3;
    int skb = (lane & 7) ^ r_in;

    if (blockIdx.x >= GRID_G) {
        // ---------------- hgemm layer-1: 64x128 tile, XCD-swizzled ----------------
        int hb = blockIdx.x - GRID_G;
        const int nit = N_NODES / 64;          // 98 i-tiles
        int per = GRID_H1 >> 3;                // 49
        int swz = (hb & 7) * per + (hb >> 3);
        int i0 = (swz % nit) * 64, j0 = (swz / nit) * 128;
        f32x4 acc[4][2] = {};
#pragma unroll 1
        for (int kk = 0; kk < CDIM; kk += 64) {
            __syncthreads();
#pragma unroll
            for (int g = 0; g < 6; g++) {      // 24 segs: A 8, B 16; 6 per wave
                int sg = wave * 6 + g;
                if (sg < 8) {
                    gld_lds16(xhi + (size_t)(i0 + sg * 8 + r_in) * CDIM + kk + skb * 8,
                              lds + sg * 1024);
                } else {
                    int seg = sg - 8;
                    gld_lds16(w1t + (size_t)(j0 + seg * 8 + r_in) * CDIM + kk + skb * 8,
                              lds + 8192 + seg * 1024);
                }
            }
            __syncthreads();
#pragma unroll
            for (int s = 0; s < 2; s++) {
                half8 a[4];
#pragma unroll
                for (int m = 0; m < 4; m++) a[m] = frag_read(lds, m * 16 + l15, s, lane);
#pragma unroll
                for (int n = 0; n < 2; n++) {
                    half8 b = frag_read(lds + 8192, wave * 32 + n * 16 + l15, s, lane);
#pragma unroll
                    for (int m = 0; m < 4; m++) acc[m][n] = MF(a[m], b, acc[m][n]);
                }
            }
        }
#pragma unroll
        for (int m = 0; m < 4; m++)
#pragma unroll
            for (int n = 0; n < 2; n++)
#pragma unroll
                for (int r = 0; r < 4; r++) {
                    int row = i0 + m * 16 + kg * 4 + r;
                    int colj = j0 + wave * 32 + n * 16 + l15;
                    hw[(size_t)row * ODIM + colj] = (_Float16)acc[m][n][r];
                }
        return;
    }

    // ---------------- gram screen ----------------
    float* S = (float*)lds;                                  // [128][33] 16.9KB
    float* topv = (float*)(lds + 16896);                     // [128][9]  4.6KB
    unsigned short* topi = (unsigned short*)(lds + 21504);   // [128][10] 2.6KB
#define TOPV(r, k) topv[(r) * 9 + (k)]
#define TOPI(r, k) topi[(r) * 10 + (k)]
    int wr = wave >> 1, wc = wave & 1;

    // bijective XCD chunking over t-major triangle raster (1225 = 8*153 + 1)
    int xcd = blockIdx.x & 7, loc = blockIdx.x >> 3;
    if (xcd != 0 && loc >= 153) return;
    int raster = (xcd == 0) ? loc : (154 + (xcd - 1) * 153 + loc);
    int t = (int)((sqrtf(8.f * (float)raster + 1.f) - 1.f) * 0.5f);
    while ((t + 1) * (t + 2) / 2 <= raster) t++;
    while (t * (t + 1) / 2 > raster) t--;
    int p = raster - t * (t + 1) / 2;                          // p <= t
    size_t i0 = (size_t)p * 128, j0 = (size_t)t * 128;

    f32x4 acc[4][4] = {};

#pragma unroll 1
    for (int c = 0; c < 32; c++) {
        int kk = c * 64;
#pragma unroll
        for (int g = 0; g < 8; g++) {      // 32 segs (8 rows x 128B), 8 per wave
            int sg = wave * 8 + g;
            int tI = sg >> 4, seg = sg & 15;
            size_t row = (tI ? j0 : i0) + (size_t)(seg * 8 + r_in);
            gld_lds16(xhi + row * CDIM + kk + skb * 8, lds + tI * 16384 + seg * 1024);
        }
        __syncthreads();
#pragma unroll
        for (int s = 0; s < 2; s++) {
            half8 a4[4];
#pragma unroll
            for (int m = 0; m < 4; m++)
                a4[m] = frag_read(lds, wr * 64 + m * 16 + l15, s, lane);
#pragma unroll
            for (int n = 0; n < 4; n++) {
                half8 b = frag_read(lds + 16384, wc * 64 + n * 16 + l15, s, lane);
#pragma unroll
                for (int m = 0; m < 4; m++) acc[m][n] = MF(a4[m], b, acc[m][n]);
            }
        }
        __syncthreads();
    }

    float sqi[4][4];
#pragma unroll
    for (int m = 0; m < 4; m++)
#pragma unroll
        for (int r = 0; r < 4; r++)
            sqi[m][r] = sq[(int)i0 + wr * 64 + m * 16 + kg * 4 + r];
    float sqj[4];
#pragma unroll
    for (int n = 0; n < 4; n++)
        sqj[n] = sq[(int)j0 + wc * 64 + n * 16 + l15];

    if (tid < 128) {
#pragma unroll
        for (int k = 0; k < 8; k++) { TOPV(tid, k) = 3.4e38f; TOPI(tid, k) = 0xFFFF; }
    }

    // ---- row pass ----
#pragma unroll
    for (int cs = 0; cs < 4; cs++) {
        __syncthreads();
        if (wc == (cs >> 1)) {
            const int n0 = (cs & 1) * 2;
#pragma unroll
            for (int m = 0; m < 4; m++)
#pragma unroll
                for (int nn = 0; nn < 2; nn++)
#pragma unroll
                    for (int r = 0; r < 4; r++) {
                        int row = wr * 64 + m * 16 + kg * 4 + r;
                        float d2 = sqi[m][r] + sqj[n0 + nn] - 2.f * acc[m][n0 + nn][r];
                        S[row * 33 + nn * 16 + l15] = d2;
                    }
        }
        __syncthreads();
        if (tid < 128) {
            int r = tid, gi = (int)i0 + r;
            int cbase = (int)j0 + cs * 32;
#pragma unroll 4
            for (int jj = 0; jj < 32; jj++) {
                int gj = cbase + jj;
                if (gj == gi) continue;
                float v = S[r * 33 + jj];
                float wv = TOPV(r, 7); int wi = TOPI(r, 7);
                if (v < wv || (v == wv && gj < wi)) {
                    int pos = 7;
                    while (pos > 0) {
                        float pv = TOPV(r, pos - 1); int pi = TOPI(r, pos - 1);
                        if (v < pv || (v == pv && gj < pi)) {
                            TOPV(r, pos) = pv; TOPI(r, pos) = (unsigned short)pi; pos--;
                        } else break;
                    }
                    TOPV(r, pos) = v; TOPI(r, pos) = (unsigned short)gj;
                }
            }
        }
    }
    __syncthreads();
    if (tid < 128) {
        int gi = (int)i0 + tid;
#pragma unroll
        for (int k = 0; k < 8; k++) {
            candv[(size_t)gi * NSLOT + t * 8 + k] = TOPV(tid, k);
            candi[(size_t)gi * NSLOT + t * 8 + k] = TOPI(tid, k);
        }
#pragma unroll
        for (int k = 0; k < 8; k++) { TOPV(tid, k) = 3.4e38f; TOPI(tid, k) = 0xFFFF; }
    }

    // ---- column pass (off-diagonal only) ----
    if (p < t) {
#pragma unroll
        for (int ss = 0; ss < 4; ss++) {
            __syncthreads();
            if (wr == (ss >> 1)) {
                const int mb = (ss & 1) * 2;
#pragma unroll
                for (int mm = 0; mm < 2; mm++)
#pragma unroll
                    for (int n = 0; n < 4; n++)
#pragma unroll
                        for (int r = 0; r < 4; r++) {
                            int rl  = mm * 16 + kg * 4 + r;
                            int col = wc * 64 + n * 16 + l15;
                            float d2 = sqi[mb + mm][r] + sqj[n] - 2.f * acc[mb + mm][n][r];
                            S[col * 33 + rl] = d2;
                        }
            }
            __syncthreads();
            if (tid < 128) {
                int cc = tid;
                int rbase = (int)i0 + ss * 32;
#pragma unroll 4
                for (int jj = 0; jj < 32; jj++) {
                    int gi = rbase + jj;
                    float v = S[cc * 33 + jj];
                    float wv = TOPV(cc, 7); int wi = TOPI(cc, 7);
                    if (v < wv || (v == wv && gi < wi)) {
                        int pos = 7;
                        while (pos > 0) {
                            float pv = TOPV(cc, pos - 1); int pi = TOPI(cc, pos - 1);
                            if (v < pv || (v == pv && gi < pi)) {
                                TOPV(cc, pos) = pv; TOPI(cc, pos) = (unsigned short)pi; pos--;
                            } else break;
                        }
                        TOPV(cc, pos) = v; TOPI(cc, pos) = (unsigned short)gi;
                    }
                }
            }
        }
        __syncthreads();
        if (tid < 128) {
            int gj = (int)j0 + tid;
#pragma unroll
            for (int k = 0; k < 8; k++) {
                candv[(size_t)gj * NSLOT + p * 8 + k] = TOPV(tid, k);
                candi[(size_t)gj * NSLOT + p * 8 + k] = TOPI(tid, k);
            }
        }
    }
#undef TOPV
#undef TOPI
}

// --- fused: merge 49 lists -> approx top-16 -> BAND-limited exact refine -> knn ---
__global__ __launch_bounds__(256) void knn_select_kernel(
        const float* __restrict__ candv, const unsigned short* __restrict__ candi,
        const float* __restrict__ x, const float* __restrict__ sq,
        int* __restrict__ knn) {
    int node = blockIdx.x * 4 + (threadIdx.x >> 6);
    int lane = threadIdx.x & 63;
    const float* cv = candv + (size_t)node * NSLOT;
    const unsigned short* ci = candi + (size_t)node * NSLOT;
    float v[7]; int ix[7];
#pragma unroll
    for (int u = 0; u < 7; u++) {
        int s = u * 64 + lane;
        bool ok = (s < NSLOT);
        v[u]  = ok ? cv[s] : 3.4e38f;
        ix[u] = ok ? (int)ci[s] : 0x7fffffff;
    }
    float myv16 = 3.4e38f; int myc = 0x7fffffff;
#pragma unroll 1
    for (int k = 0; k < 16; k++) {
        float bv = v[0]; int bi = ix[0];
#pragma unroll
        for (int u = 1; u < 7; u++)
            if (v[u] < bv || (v[u] == bv && ix[u] < bi)) { bv = v[u]; bi = ix[u]; }
#pragma unroll
        for (int off = 32; off; off >>= 1) {
            float ov = __shfl_xor(bv, off, 64);
            int   oi = __shfl_xor(bi, off, 64);
            if (ov < bv || (ov == bv && oi < bi)) { bv = ov; bi = oi; }
        }
        if (lane == k) { myv16 = bv; myc = bi; }
#pragma unroll
        for (int u = 0; u < 7; u++)
            if (ix[u] == bi) { v[u] = 3.4e38f; ix[u] = 0x7fffffff; }
    }
    float v7 = __shfl(myv16, 7, 64), v8 = __shfl(myv16, 8, 64);
    if (v8 - v7 > E2) {                            // fast path: set provably exact
        if (lane < 8) knn[(size_t)node * 8 + lane] = myc;
        return;
    }
    bool isc  = (lane < 16);
    bool cin  = isc && (myv16 < v7 - E2);
    bool cout = isc && (myv16 > v8 + E2);
    bool band = isc && !cin && !cout;
    unsigned long long bm = __ballot(band);
    float fv = myv16;
    if (cin)  fv = myv16 - 1e9f;
    if (cout) fv = myv16 + 1e9f;

    const float* xi = x + (size_t)node * CDIM;
    float4 a[8];
#pragma unroll
    for (int g = 0; g < 8; g++) a[g] = *(const float4*)(xi + (g * 64 + lane) * 4);
    float sqi = sq[node];
#pragma unroll 1
    for (int c = 0; c < 16; c++) {
        if (!((bm >> c) & 1ull)) continue;
        int j = __shfl(myc, c, 64);
        const float* xj = x + (size_t)j * CDIM;
        float s = 0.f;
#pragma unroll
        for (int g = 0; g < 8; g++) {
            float4 b = *(const float4*)(xj + (g * 64 + lane) * 4);
            s = fmaf(a[g].x, b.x, s); s = fmaf(a[g].y, b.y, s);
            s = fmaf(a[g].z, b.z, s); s = fmaf(a[g].w, b.w, s);
        }
#pragma unroll
        for (int off = 32; off; off >>= 1) s += __shfl_down(s, off, 64);
        float d2 = sqi + sq[j] - 2.f * s;
        d2 = __shfl(d2, 0, 64);
        if (lane == c) fv = d2;
    }
    float rv = (lane < 16) ? fv : 3.4e38f;
    int   ri = (lane < 16) ? myc : 0x7fffffff;
#pragma unroll 1
    for (int k = 0; k < 8; k++) {
        float bv = rv; int bi = ri;
#pragma unroll
        for (int off = 8; off; off >>= 1) {
            float ov = __shfl_xor(bv, off, 64);
            int   oi = __shfl_xor(bi, off, 64);
            if (ov < bv || (ov == bv && oi < bi)) { bv = ov; bi = oi; }
        }
        bv = __shfl(bv, lane & 15, 64); bi = __shfl(bi, lane & 15, 64);
        if (lane == 0) knn[(size_t)node * 8 + k] = bi;
        if (ri == bi) { rv = 3.4e38f; ri = 0x7fffffff; }
    }
}

// ------------- graph build: parallel 4-kernel pipeline -------------
__global__ __launch_bounds__(256) void graph_init_kernel(int* deg, int* cnt) {
    int i = blockIdx.x * 256 + threadIdx.x;
    if (i < N_NODES) { deg[i] = 1; cnt[i] = 0; }
}
__global__ __launch_bounds__(256) void deg_count_kernel(const int* __restrict__ knn,
                                                        int* deg) {
    int e = blockIdx.x * 256 + threadIdx.x;
    if (e < N_NODES * 8) atomicAdd(&deg[knn[e]], 1);
}
__global__ __launch_bounds__(1024) void scan_dinv_kernel(const int* __restrict__ deg,
        float* __restrict__ dinv, int* __restrict__ row_ptr) {
    __shared__ int partial[1024];
    const int CH = 7;
    int tid = threadIdx.x;
    int start = tid * CH;
    int end = start + CH; if (end > N_NODES) end = N_NODES;
    int s = 0;
    for (int i = start; i < end; i++) s += deg[i];
    partial[tid] = s;
    __syncthreads();
    if (tid == 0) {
        int run = 0;
        for (int k = 0; k < 1024; k++) { int vv = partial[k]; partial[k] = run; run += vv; }
        row_ptr[N_NODES] = run;
    }
    __syncthreads();
    int run = partial[tid];
    for (int i = start; i < end; i++) {
        row_ptr[i] = run;
        dinv[i] = rsqrtf((float)deg[i]);
        run += deg[i];
    }
}
__global__ __launch_bounds__(256) void scatter_kernel(const int* __restrict__ knn,
        const int* __restrict__ row_ptr, int* cnt, int* __restrict__ col) {
    int i = blockIdx.x * 256 + threadIdx.x;
    if (i >= N_NODES) return;
    int p0 = row_ptr[i] + atomicAdd(&cnt[i], 1);
    col[p0] = i;                                   // self-loop
#pragma unroll
    for (int j = 0; j < 8; j++) {
        int d = knn[(size_t)i * 8 + j];
        int q = row_ptr[d] + atomicAdd(&cnt[d], 1);
        col[q] = i;
    }
}

// ---- fp16 MFMA GEMM, 64x128 tiles, f16 out, XCD-swizzled (layer 2, K=512) ----
__global__ __launch_bounds__(256) void hgemm_nt_kernel(
        const _Float16* __restrict__ A, const _Float16* __restrict__ Bt,
        _Float16* __restrict__ C, int M, int N, int K) {
    __shared__ char lds[24576];        // A 8KB | B 16KB
    int tid = threadIdx.x, lane = tid & 63, wave = tid >> 6;
    int l15 = lane & 15, kg = lane >> 4;
    int nt = N >> 7;
    int nblk = (M >> 6) * nt;
    int per = nblk >> 3;
    int swz = (blockIdx.x & 7) * per + (blockIdx.x >> 3);
    int i0 = (swz % (M >> 6)) * 64, j0 = (swz / (M >> 6)) * 128;
    f32x4 acc[4][2] = {};

    int r_in = lane >> 3;
    int skb = (lane & 7) ^ r_in;

#pragma unroll 1
    for (int kk = 0; kk < K; kk += 64) {
        __syncthreads();
#pragma unroll
        for (int g = 0; g < 6; g++) {
            int sg = wave * 6 + g;
            if (sg < 8) {
                gld_lds16(A + (size_t)(i0 + sg * 8 + r_in) * K + kk + skb * 8,
                          lds + sg * 1024);
            } else {
                int seg = sg - 8;
                gld_lds16(Bt + (size_t)(j0 + seg * 8 + r_in) * K + kk + skb * 8,
                          lds + 8192 + seg * 1024);
            }
        }
        __syncthreads();
#pragma unroll
        for (int s = 0; s < 2; s++) {
            half8 a[4];
#pragma unroll
            for (int m = 0; m < 4; m++) a[m] = frag_read(lds, m * 16 + l15, s, lane);
#pragma unroll
            for (int n = 0; n < 2; n++) {
                half8 b = frag_read(lds + 8192, wave * 32 + n * 16 + l15, s, lane);
#pragma unroll
                for (int m = 0; m < 4; m++) acc[m][n] = MF(a[m], b, acc[m][n]);
            }
        }
    }
#pragma unroll
    for (int m = 0; m < 4; m++)
#pragma unroll
        for (int n = 0; n < 2; n++)
#pragma unroll
            for (int r = 0; r < 4; r++) {
                int row = i0 + m * 16 + kg * 4 + r;
                int colj = j0 + wave * 32 + n * 16 + l15;
                C[(size_t)row * N + colj] = (_Float16)acc[m][n][r];
            }
}

// --- GCN aggregation (f16 in): out[d] = relu(dinv[d]*sum hw[s]*dinv[s] + b) ---
template <bool HALF_OUT>
__global__ __launch_bounds__(256) void aggregate_kernel(
        const _Float16* __restrict__ hw, const int* __restrict__ row_ptr,
        const int* __restrict__ col, const float* __restrict__ dinv,
        const float* __restrict__ bias, void* __restrict__ outp) {
    int node = blockIdx.x * 4 + (threadIdx.x >> 6);
    int lane = threadIdx.x & 63;
    int e0 = row_ptr[node], e1 = row_ptr[node + 1];
    float acc[8] = {};
    for (int e = e0; e < e1; e++) {
        int s = col[e];
        float w = dinv[s];
        half8 v = *(const half8*)(hw + (size_t)s * ODIM + lane * 8);
#pragma unroll
        for (int j = 0; j < 8; j++) acc[j] = fmaf(w, (float)v[j], acc[j]);
    }
    float wd = dinv[node];
    float4 b0 = *(const float4*)(bias + lane * 8);
    float4 b1 = *(const float4*)(bias + lane * 8 + 4);
    float o[8];
    o[0] = fmaxf(fmaf(acc[0], wd, b0.x), 0.f);
    o[1] = fmaxf(fmaf(acc[1], wd, b0.y), 0.f);
    o[2] = fmaxf(fmaf(acc[2], wd, b0.z), 0.f);
    o[3] = fmaxf(fmaf(acc[3], wd, b0.w), 0.f);
    o[4] = fmaxf(fmaf(acc[4], wd, b1.x), 0.f);
    o[5] = fmaxf(fmaf(acc[5], wd, b1.y), 0.f);
    o[6] = fmaxf(fmaf(acc[6], wd, b1.z), 0.f);
    o[7] = fmaxf(fmaf(acc[7], wd, b1.w), 0.f);
    if (HALF_OUT) {
        half8 h;
#pragma unroll
        for (int j = 0; j < 8; j++) h[j] = (_Float16)o[j];
        *(half8*)((_Float16*)outp + (size_t)node * ODIM + lane * 8) = h;
    } else {
        float* out = (float*)outp;
        float4 f0 = {o[0], o[1], o[2], o[3]}, f1 = {o[4], o[5], o[6], o[7]};
        *(float4*)(out + (size_t)node * ODIM + lane * 8)     = f0;
        *(float4*)(out + (size_t)node * ODIM + lane * 8 + 4) = f1;
    }
}

extern "C" void kernel_launch(void* const* d_in, const int* in_sizes, int n_in,
                              void* d_out, int out_size, void* d_ws, size_t ws_size,
                              hipStream_t stream) {
    const float* x  = (const float*)d_in[0];
    const float* W1 = (const float*)d_in[1];
    const float* b1 = (const float*)d_in[2];
    const float* W2 = (const float*)d_in[3];
    const float* b2 = (const float*)d_in[4];
    float* out = (float*)d_out;
    char* ws = (char*)d_ws;

    _Float16* xhi  = (_Float16*)(ws + XHI_OFF);
    float* candv   = (float*)(ws + CANDV_OFF);
    unsigned short* candi = (unsigned short*)(ws + CANDI_OFF);
    float* sq      = (float*)(ws + SQ_OFF);
    int*   knn     = (int*)  (ws + KNN_OFF);
    int*   cnt     = (int*)  (ws + CNT_OFF);
    int*   deg     = (int*)  (ws + DEG_OFF);
    float* dinv    = (float*)(ws + DINV_OFF);
    int*   row_ptr = (int*)  (ws + RPTR_OFF);
    int*   col     = (int*)  (ws + COL_OFF);
    _Float16* w1t  = (_Float16*)(ws + W1T_OFF);
    _Float16* w2t  = (_Float16*)(ws + W2T_OFF);
    _Float16* hw   = (_Float16*)(ws + HW_OFF);
    _Float16* h1h  = (_Float16*)(ws + H1H_OFF);

    prep_kernel<<<1888, 256, 0, stream>>>(x, xhi, sq, W1, w1t, W2, w2t);
    gram_hgemm_kernel<<<GRID_G + GRID_H1, 256, 0, stream>>>(xhi, sq, candv, candi, w1t, hw);
    knn_select_kernel<<<N_NODES / 4, 256, 0, stream>>>(candv, candi, x, sq, knn);

    graph_init_kernel<<<(N_NODES + 255) / 256, 256, 0, stream>>>(deg, cnt);
    deg_count_kernel<<<(N_NODES * 8) / 256, 256, 0, stream>>>(knn, deg);
    scan_dinv_kernel<<<1, 1024, 0, stream>>>(deg, dinv, row_ptr);
    scatter_kernel<<<(N_NODES + 255) / 256, 256, 0, stream>>>(knn, row_ptr, cnt, col);

    aggregate_kernel<true><<<N_NODES / 4, 256, 0, stream>>>(hw, row_ptr, col, dinv, b1, (void*)h1h);
    hgemm_nt_kernel<<<(N_NODES / 64) * (ODIM / 128), 256, 0, stream>>>(h1h, w2t, hw, N_NODES, ODIM, ODIM);
    aggregate_kernel<false><<<N_NODES / 4, 256, 0, stream>>>(hw, row_ptr, col, dinv, b2, (void*)out);
}